// Round 5
// baseline (1018.781 us; speedup 1.0000x reference)
//
#include <hip/hip_runtime.h>
#include <math.h>

// GCN 2-layer + FC + global_add_pool + log_softmax.
// Round 5: two-level counting sort replaces single-pass build_k whose random
// 8B stores caused 8x HBM write amplification (200MB for 25.6MB payload).
// bin1 appends packed 4B (row<<6|col&63) into per-bucket (64-node) regions of
// the final ordering; bin2 places {row,weight} within its L2-hot 16KB window.

#define NF_IN 128
#define HID1 16
#define NPB 64          // nodes per bucket (pow2, shift=6)

// ---- int histogram of col ----
__global__ void hist_k(const int* __restrict__ col, int* __restrict__ deg,
                       int E, int N) {
    int e = blockIdx.x * blockDim.x + threadIdx.x;
    if (e < E) {
        int c = col[e];
        if ((unsigned)c < (unsigned)N) atomicAdd(&deg[c], 1);
    }
}

// ---- scan stage 1: per-block (256 elems) partial sums ----
__global__ __launch_bounds__(256) void partial_k(const int* __restrict__ deg,
                                                 int* __restrict__ partials, int N) {
    __shared__ int lds[256];
    int t = threadIdx.x;
    int i = blockIdx.x * 256 + t;
    lds[t] = (i < N) ? deg[i] : 0;
    __syncthreads();
    for (int off = 128; off > 0; off >>= 1) {
        if (t < off) lds[t] += lds[t + off];
        __syncthreads();
    }
    if (t == 0) partials[blockIdx.x] = lds[0];
}

// ---- scan stage 2: one block scans B<=512 partials -> exclusive offsets ----
__global__ __launch_bounds__(512) void scanp_k(const int* __restrict__ partials,
                                               int* __restrict__ offsets, int B) {
    __shared__ int lds[512];
    int t = threadIdx.x;
    int v = (t < B) ? partials[t] : 0;
    lds[t] = v;
    __syncthreads();
    for (int off = 1; off < 512; off <<= 1) {
        int u = (t >= off) ? lds[t - off] : 0;
        __syncthreads();
        lds[t] += u;
        __syncthreads();
    }
    if (t < B) offsets[t] = lds[t] - v;
    if (t == B - 1) offsets[B] = lds[t];
}

// ---- scan stage 3: per-block exclusive scan + offset; fused dinv ----
__global__ __launch_bounds__(256) void apply_k(const int* __restrict__ deg,
                                               const int* __restrict__ offsets,
                                               int* __restrict__ starts,
                                               int* __restrict__ cursor,
                                               float* __restrict__ dinv,
                                               int N, int B) {
    __shared__ int lds[256];
    int t = threadIdx.x;
    int i = blockIdx.x * 256 + t;
    int d = (i < N) ? deg[i] : 0;
    lds[t] = d;
    __syncthreads();
    for (int off = 1; off < 256; off <<= 1) {
        int u = (t >= off) ? lds[t - off] : 0;
        __syncthreads();
        lds[t] += u;
        __syncthreads();
    }
    int excl = lds[t] - d + offsets[blockIdx.x];
    if (i < N) {
        starts[i] = excl;
        cursor[i] = excl;
        dinv[i] = rsqrtf((float)d + 1.0f);
    }
    if (i == 0) starts[N] = offsets[B];
}

// ---- seed bucket cursors from starts ----
__global__ void bcur_k(const int* __restrict__ starts, int* __restrict__ bcur,
                       int nb, int N) {
    int b = blockIdx.x * blockDim.x + threadIdx.x;
    if (b < nb) bcur[b] = starts[min(b * NPB, N)];
}

// ---- bin pass 1: append packed (row<<6 | col&63) into bucket region ----
__global__ void bin1_k(const int* __restrict__ row, const int* __restrict__ col,
                       int* __restrict__ bcur, int* __restrict__ staging,
                       int E, int N) {
    int e = blockIdx.x * blockDim.x + threadIdx.x;
    if (e >= E) return;
    int r = row[e], c = col[e];
    if ((unsigned)r >= (unsigned)N || (unsigned)c >= (unsigned)N) return;
    int slot = atomicAdd(&bcur[c >> 6], 1);
    staging[slot] = (r << 6) | (c & (NPB - 1));
}

// ---- bin pass 2: within-bucket placement; final entry {row, weight} ----
__global__ __launch_bounds__(256) void bin2_k(const int* __restrict__ staging,
                                              const int* __restrict__ starts,
                                              const float* __restrict__ dinv,
                                              int* __restrict__ cursor,
                                              int2* __restrict__ sorted,
                                              int N) {
    int base_node = blockIdx.x * NPB;
    int s = starts[base_node];
    int e = starts[min(base_node + NPB, N)];
    for (int i = s + (int)threadIdx.x; i < e; i += 256) {
        int pk = staging[i];
        int r = pk >> 6;
        int c = base_node + (pk & (NPB - 1));
        float w = dinv[r] * dinv[c];
        int slot = atomicAdd(&cursor[c], 1);
        sorted[slot] = make_int2(r, __float_as_int(w));
    }
}

// ---- h1 = x @ W1  [N,128]@[128,16]; 16 nodes per 256-thread block ----
__global__ __launch_bounds__(256) void xw1_k(const float* __restrict__ x,
                                             const float* __restrict__ W1,
                                             float* __restrict__ h1, int N) {
    __shared__ float w[NF_IN * HID1];
    __shared__ float xs[16 * NF_IN];
    int t = threadIdx.x;
    for (int i = t; i < NF_IN * HID1; i += 256) w[i] = W1[i];
    int base = blockIdx.x * 16;
    int navail = min(16, N - base);
    const float* xp = x + (size_t)base * NF_IN;
    for (int i = t; i < navail * NF_IN; i += 256) xs[i] = xp[i];
    __syncthreads();
    int nl = t >> 4, j = t & 15;
    if (base + nl < N) {
        float acc = 0.0f;
        const float* xrow = &xs[nl * NF_IN];
        #pragma unroll 8
        for (int k = 0; k < NF_IN; ++k) acc += xrow[k] * w[k * HID1 + j];
        h1[(size_t)(base + nl) * HID1 + j] = acc;
    }
}

// ---- gather: dst[n] = sum src[r]*w + src[n]*dinv[n]^2 (+bias, relu) ----
__global__ __launch_bounds__(256) void gather16(const int2* __restrict__ sorted,
                                                const int* __restrict__ starts,
                                                const float* __restrict__ dinv,
                                                const float* __restrict__ src,
                                                const float* __restrict__ bias,
                                                float* __restrict__ dst,
                                                int N, int relu_mode) {
    int t = blockIdx.x * blockDim.x + threadIdx.x;
    int n = t >> 2, part = t & 3;
    if (n >= N) return;
    int s = starts[n], e = starts[n + 1];
    float4 acc = make_float4(0.f, 0.f, 0.f, 0.f);
    for (int i = s; i < e; ++i) {
        int2 en = sorted[i];
        float w = __int_as_float(en.y);
        float4 m = ((const float4*)(src + (size_t)en.x * HID1))[part];
        acc.x += m.x * w; acc.y += m.y * w;
        acc.z += m.z * w; acc.w += m.w * w;
    }
    float d = dinv[n], d2 = d * d;
    float4 sf = ((const float4*)(src + (size_t)n * HID1))[part];
    acc.x += sf.x * d2; acc.y += sf.y * d2;
    acc.z += sf.z * d2; acc.w += sf.w * d2;
    if (relu_mode) {
        float4 b = ((const float4*)bias)[part];
        acc.x = fmaxf(acc.x + b.x, 0.f);
        acc.y = fmaxf(acc.y + b.y, 0.f);
        acc.z = fmaxf(acc.z + b.z, 0.f);
        acc.w = fmaxf(acc.w + b.w, 0.f);
    }
    ((float4*)(dst + (size_t)n * HID1))[part] = acc;
}

// ---- epilogue: y = relu(v@W2 + b2); p = y@fcW; block-reduce; atomic pool ----
__global__ __launch_bounds__(256) void final_k(const float* __restrict__ v2,
                                               const float* __restrict__ W2,
                                               const float* __restrict__ b2,
                                               const float* __restrict__ fcW,
                                               float* __restrict__ pooled, int N) {
    __shared__ float w2[HID1 * 64];
    __shared__ float fw[64 * 2];
    __shared__ float bb[64];
    int t = threadIdx.x;
    for (int i = t; i < HID1 * 64; i += 256) w2[i] = W2[i];
    if (t < 128) fw[t] = fcW[t];
    if (t < 64) bb[t] = b2[t];
    __syncthreads();
    int n = blockIdx.x * blockDim.x + t;
    float p0 = 0.0f, p1 = 0.0f;
    if (n < N) {
        float v[HID1];
        const float4* a4 = (const float4*)(v2 + (size_t)n * HID1);
        #pragma unroll
        for (int q = 0; q < 4; ++q) {
            float4 a = a4[q];
            v[q * 4 + 0] = a.x; v[q * 4 + 1] = a.y;
            v[q * 4 + 2] = a.z; v[q * 4 + 3] = a.w;
        }
        #pragma unroll 4
        for (int j = 0; j < 64; ++j) {
            float acc = bb[j];
            #pragma unroll
            for (int k = 0; k < HID1; ++k) acc += v[k] * w2[k * 64 + j];
            float y = fmaxf(acc, 0.0f);
            p0 += y * fw[j * 2 + 0];
            p1 += y * fw[j * 2 + 1];
        }
    }
    for (int off = 32; off > 0; off >>= 1) {
        p0 += __shfl_down(p0, off);
        p1 += __shfl_down(p1, off);
    }
    __shared__ float r0[4], r1[4];
    int wid = t >> 6, lane = t & 63;
    if (lane == 0) { r0[wid] = p0; r1[wid] = p1; }
    __syncthreads();
    if (t == 0) {
        atomicAdd(&pooled[0], r0[0] + r0[1] + r0[2] + r0[3]);
        atomicAdd(&pooled[1], r1[0] + r1[1] + r1[2] + r1[3]);
    }
}

// ---- log_softmax over pooled[2] + N*fcb ----
__global__ void logsm_k(const float* __restrict__ pooled,
                        const float* __restrict__ fcb,
                        float* __restrict__ out, float Nf) {
    if (threadIdx.x == 0 && blockIdx.x == 0) {
        float p0 = pooled[0] + Nf * fcb[0];
        float p1 = pooled[1] + Nf * fcb[1];
        float m = fmaxf(p0, p1);
        float lse = m + logf(expf(p0 - m) + expf(p1 - m));
        out[0] = p0 - lse;
        out[1] = p1 - lse;
    }
}

extern "C" void kernel_launch(void* const* d_in, const int* in_sizes, int n_in,
                              void* d_out, int out_size, void* d_ws, size_t ws_size,
                              hipStream_t stream) {
    const float* x   = (const float*)d_in[0];
    const int*   ei  = (const int*)d_in[1];
    const float* W1  = (const float*)d_in[2];
    const float* b1  = (const float*)d_in[3];
    const float* W2  = (const float*)d_in[4];
    const float* b2  = (const float*)d_in[5];
    const float* fcW = (const float*)d_in[6];
    const float* fcb = (const float*)d_in[7];
    float* out = (float*)d_out;

    int N = in_sizes[0] / NF_IN;
    int E = in_sizes[1] / 2;
    const int* row = ei;
    const int* col = ei + E;

    int B  = (N + 255) / 256;           // scan blocks (<=512)
    int nb = (N + NPB - 1) / NPB;       // buckets

    // ws layout (4B units):
    // [deg N | starts N+1 pad | cursor N | dinv N | h1 16N | z1 16N | pooled 2 |
    //  sorted 2E | partials B | offsets B+1 | bcur nb | (staging E if room)]
    int*   ws_i   = (int*)d_ws;
    float* ws_f   = (float*)d_ws;
    int*   deg_i  = ws_i;
    int*   starts = ws_i + (size_t)N;
    int*   cursor = ws_i + (size_t)2 * N + 2;
    float* dinv   = ws_f + (size_t)3 * N + 2;
    float* h1     = ws_f + (size_t)4 * N + 2;   // also v2 (gather2 out)
    float* z1     = ws_f + (size_t)20 * N + 2;
    float* pooled = ws_f + (size_t)36 * N + 2;
    int2*  sorted = (int2*)(ws_f + (size_t)36 * N + 4);
    int*   partials = (int*)(sorted + (size_t)E);
    int*   offsets  = partials + B;
    int*   bcur     = offsets + B + 1;

    // staging: tail if ws_size allows, else alias h1/z1 (dead until xw1_k,
    // which runs after bin2_k; requires E <= 32N — true here: E == 32N).
    size_t tail_need = ((size_t)36 * N + 4 + 2 * (size_t)E + B + B + 1 + nb
                        + (size_t)E) * 4;
    int* staging = (ws_size >= tail_need) ? (bcur + nb) : (int*)h1;

    hipMemsetAsync(deg_i, 0, (size_t)N * sizeof(int), stream);
    hipMemsetAsync(pooled, 0, 2 * sizeof(float), stream);

    int b = 256;
    hist_k<<<(E + b - 1) / b, b, 0, stream>>>(col, deg_i, E, N);
    partial_k<<<B, 256, 0, stream>>>(deg_i, partials, N);
    scanp_k<<<1, 512, 0, stream>>>(partials, offsets, B);
    apply_k<<<B, 256, 0, stream>>>(deg_i, offsets, starts, cursor, dinv, N, B);
    bcur_k<<<(nb + b - 1) / b, b, 0, stream>>>(starts, bcur, nb, N);
    bin1_k<<<(E + b - 1) / b, b, 0, stream>>>(row, col, bcur, staging, E, N);
    bin2_k<<<nb, 256, 0, stream>>>(staging, starts, dinv, cursor, sorted, N);
    xw1_k<<<(N + 15) / 16, b, 0, stream>>>(x, W1, h1, N);
    long long t4 = (long long)N * 4;
    gather16<<<(int)((t4 + b - 1) / b), b, 0, stream>>>(
        sorted, starts, dinv, h1, b1, z1, N, 1);
    gather16<<<(int)((t4 + b - 1) / b), b, 0, stream>>>(
        sorted, starts, dinv, z1, b1, h1, N, 0);
    final_k<<<(N + b - 1) / b, b, 0, stream>>>(h1, W2, b2, fcW, pooled, N);
    logsm_k<<<1, 64, 0, stream>>>(pooled, fcb, out, (float)N);
}

// Round 6
// 364.749 us; speedup vs baseline: 2.7931x; 2.7931x over previous
//
#include <hip/hip_runtime.h>
#include <math.h>

// GCN 2-layer + FC + global_add_pool + log_softmax.
// Round 6: contention-free counting sort (LDS histograms, per-block bucket
// reservation, line-dense writes) + weight elimination via dinv pre-scaling
// (CSR = 4B row indices only). R5's bin1_k (per-edge atomics on 1563 global
// counters, 230ns serialized each) is the anti-pattern this replaces.

#define NF_IN 128
#define HID1 16
#define BSH 8                 // 256 nodes per coarse bucket
#define BPB 256               // nodes per bucket
#define EPB 8192              // edges per partition block (256 thr x 32)
#define MAXNB 1024            // supports N <= 262144

// ---- pass A: per-block LDS histogram of col>>8, merge to global counts ----
__global__ __launch_bounds__(256) void cnt1_k(const int* __restrict__ col,
                                              int* __restrict__ gbcnt,
                                              int E, int N, int nb) {
    __shared__ int lh[MAXNB];
    int t = threadIdx.x;
    for (int i = t; i < nb; i += 256) lh[i] = 0;
    __syncthreads();
    int base = blockIdx.x * EPB;
    for (int k = 0; k < 32; ++k) {
        int e = base + k * 256 + t;
        if (e < E) {
            int c = col[e];
            if ((unsigned)c < (unsigned)N) atomicAdd(&lh[c >> BSH], 1);
        }
    }
    __syncthreads();
    for (int i = t; i < nb; i += 256) {
        int v = lh[i];
        if (v) atomicAdd(&gbcnt[i], v);
    }
}

// ---- pass B: one block scans nb (<=512) bucket counts ----
__global__ __launch_bounds__(512) void bscan_k(const int* __restrict__ gbcnt,
                                               int* __restrict__ bstarts,
                                               int* __restrict__ gcur, int nb) {
    __shared__ int lds[512];
    int t = threadIdx.x;
    int v = (t < nb) ? gbcnt[t] : 0;
    lds[t] = v;
    __syncthreads();
    for (int off = 1; off < 512; off <<= 1) {
        int u = (t >= off) ? lds[t - off] : 0;
        __syncthreads();
        lds[t] += u;
        __syncthreads();
    }
    if (t < nb) {
        int excl = lds[t] - v;
        bstarts[t] = excl;
        gcur[t] = excl;
    }
    if (t == nb - 1) bstarts[nb] = lds[t];
}

// ---- pass C: re-read edges; LDS hist; one global reservation per bucket
//      per block; place packed (r<<8 | c&255) via LDS cursors ----
__global__ __launch_bounds__(256) void place_k(const int* __restrict__ row,
                                               const int* __restrict__ col,
                                               int* __restrict__ gcur,
                                               int* __restrict__ staging,
                                               int E, int N, int nb) {
    __shared__ int lh[MAXNB];
    int t = threadIdx.x;
    for (int i = t; i < nb; i += 256) lh[i] = 0;
    __syncthreads();
    int base = blockIdx.x * EPB;
    for (int k = 0; k < 32; ++k) {
        int e = base + k * 256 + t;
        if (e < E) {
            int c = col[e];
            if ((unsigned)c < (unsigned)N) atomicAdd(&lh[c >> BSH], 1);
        }
    }
    __syncthreads();
    // reserve: lh[i] becomes this block's write cursor for bucket i
    for (int i = t; i < nb; i += 256) {
        int cnt = lh[i];
        lh[i] = cnt ? atomicAdd(&gcur[i], cnt) : 0;
    }
    __syncthreads();
    for (int k = 0; k < 32; ++k) {
        int e = base + k * 256 + t;
        if (e < E) {
            int r = row[e], c = col[e];
            if ((unsigned)r < (unsigned)N && (unsigned)c < (unsigned)N) {
                int slot = atomicAdd(&lh[c >> BSH], 1);
                staging[slot] = (r << BSH) | (c & (BPB - 1));
            }
        }
    }
}

// ---- pass D: one block per bucket: per-node count + LDS scan -> starts,
//      dinv, and exact row-sorted placement (all writes in a dense window) ----
__global__ __launch_bounds__(256) void node_k(const int* __restrict__ staging,
                                              const int* __restrict__ bstarts,
                                              int* __restrict__ starts,
                                              float* __restrict__ dinv,
                                              int* __restrict__ sorted,
                                              int N, int nb) {
    __shared__ int lcnt[BPB];
    __shared__ int lscan[BPB];
    __shared__ int lcur[BPB];
    int t = threadIdx.x;
    int bk = blockIdx.x;
    int node = bk * BPB + t;
    lcnt[t] = 0;
    __syncthreads();
    int s = bstarts[bk], e = bstarts[bk + 1];
    for (int i = s + t; i < e; i += 256)
        atomicAdd(&lcnt[staging[i] & (BPB - 1)], 1);
    __syncthreads();
    int d = lcnt[t];
    lscan[t] = d;
    __syncthreads();
    for (int off = 1; off < 256; off <<= 1) {
        int u = (t >= off) ? lscan[t - off] : 0;
        __syncthreads();
        lscan[t] += u;
        __syncthreads();
    }
    int excl = s + lscan[t] - d;
    lcur[t] = excl;
    if (node < N) {
        starts[node] = excl;
        dinv[node] = rsqrtf((float)d + 1.0f);
    }
    if (bk == nb - 1 && t == 0) starts[N] = e;
    __syncthreads();
    for (int i = s + t; i < e; i += 256) {
        int pk = staging[i];
        int slot = atomicAdd(&lcur[pk & (BPB - 1)], 1);
        sorted[slot] = pk >> BSH;
    }
}

// ---- h1' = (x @ W1) * dinv  [N,128]@[128,16]; 16 nodes/block ----
__global__ __launch_bounds__(256) void xw1_k(const float* __restrict__ x,
                                             const float* __restrict__ W1,
                                             const float* __restrict__ dinv,
                                             float* __restrict__ h1p, int N) {
    __shared__ float w[NF_IN * HID1];
    __shared__ float xs[16 * NF_IN];
    int t = threadIdx.x;
    for (int i = t; i < NF_IN * HID1; i += 256) w[i] = W1[i];
    int base = blockIdx.x * 16;
    int navail = min(16, N - base);
    const float* xp = x + (size_t)base * NF_IN;
    for (int i = t; i < navail * NF_IN; i += 256) xs[i] = xp[i];
    __syncthreads();
    int nl = t >> 4, j = t & 15;
    int n = base + nl;
    if (n < N) {
        float acc = 0.0f;
        const float* xrow = &xs[nl * NF_IN];
        #pragma unroll 8
        for (int k = 0; k < NF_IN; ++k) acc += xrow[k] * w[k * HID1 + j];
        h1p[(size_t)n * HID1 + j] = acc * dinv[n];
    }
}

// ---- gather (weightless CSR): acc = sum src[r] (+ src[n] self) ;
//  mode1: out = relu(dinv*acc + b) * dinv   (z1' for next layer)
//  mode0: out = dinv*acc                    (v2 for final_k)
// 4 threads/node; quad-shuffle shares each 4B edge entry across the quad. ----
__global__ __launch_bounds__(256) void gather16(const int* __restrict__ sorted,
                                                const int* __restrict__ starts,
                                                const float* __restrict__ dinv,
                                                const float* __restrict__ src,
                                                const float* __restrict__ bias,
                                                float* __restrict__ dst,
                                                int N, int relu_mode) {
    int t = blockIdx.x * blockDim.x + threadIdx.x;
    int n = t >> 2, part = t & 3;
    if (n >= N) return;
    int s = starts[n], e = starts[n + 1];
    float4 acc = make_float4(0.f, 0.f, 0.f, 0.f);
    for (int i0 = s; i0 < e; i0 += 4) {
        int mi = i0 + part;
        int rmine = (mi < e) ? sorted[mi] : -1;
        #pragma unroll
        for (int j = 0; j < 4; ++j) {
            int rj = __shfl(rmine, j, 4);
            if (rj >= 0) {
                float4 m = ((const float4*)(src + (size_t)rj * HID1))[part];
                acc.x += m.x; acc.y += m.y; acc.z += m.z; acc.w += m.w;
            }
        }
    }
    float4 sf = ((const float4*)(src + (size_t)n * HID1))[part];
    acc.x += sf.x; acc.y += sf.y; acc.z += sf.z; acc.w += sf.w;
    float dn = dinv[n];
    if (relu_mode) {
        float4 b = ((const float4*)bias)[part];
        acc.x = fmaxf(acc.x * dn + b.x, 0.f) * dn;
        acc.y = fmaxf(acc.y * dn + b.y, 0.f) * dn;
        acc.z = fmaxf(acc.z * dn + b.z, 0.f) * dn;
        acc.w = fmaxf(acc.w * dn + b.w, 0.f) * dn;
    } else {
        acc.x *= dn; acc.y *= dn; acc.z *= dn; acc.w *= dn;
    }
    ((float4*)(dst + (size_t)n * HID1))[part] = acc;
}

// ---- epilogue: y = relu(v@W2 + b2); p = y@fcW; reduce; atomic pool ----
__global__ __launch_bounds__(256) void final_k(const float* __restrict__ v2,
                                               const float* __restrict__ W2,
                                               const float* __restrict__ b2,
                                               const float* __restrict__ fcW,
                                               float* __restrict__ pooled, int N) {
    __shared__ float w2[HID1 * 64];
    __shared__ float fw[64 * 2];
    __shared__ float bb[64];
    int t = threadIdx.x;
    for (int i = t; i < HID1 * 64; i += 256) w2[i] = W2[i];
    if (t < 128) fw[t] = fcW[t];
    if (t < 64) bb[t] = b2[t];
    __syncthreads();
    int n = blockIdx.x * blockDim.x + t;
    float p0 = 0.0f, p1 = 0.0f;
    if (n < N) {
        float v[HID1];
        const float4* a4 = (const float4*)(v2 + (size_t)n * HID1);
        #pragma unroll
        for (int q = 0; q < 4; ++q) {
            float4 a = a4[q];
            v[q * 4 + 0] = a.x; v[q * 4 + 1] = a.y;
            v[q * 4 + 2] = a.z; v[q * 4 + 3] = a.w;
        }
        #pragma unroll 4
        for (int j = 0; j < 64; ++j) {
            float acc = bb[j];
            #pragma unroll
            for (int k = 0; k < HID1; ++k) acc += v[k] * w2[k * 64 + j];
            float y = fmaxf(acc, 0.0f);
            p0 += y * fw[j * 2 + 0];
            p1 += y * fw[j * 2 + 1];
        }
    }
    for (int off = 32; off > 0; off >>= 1) {
        p0 += __shfl_down(p0, off);
        p1 += __shfl_down(p1, off);
    }
    __shared__ float r0[4], r1[4];
    int wid = t >> 6, lane = t & 63;
    if (lane == 0) { r0[wid] = p0; r1[wid] = p1; }
    __syncthreads();
    if (t == 0) {
        atomicAdd(&pooled[0], r0[0] + r0[1] + r0[2] + r0[3]);
        atomicAdd(&pooled[1], r1[0] + r1[1] + r1[2] + r1[3]);
    }
}

// ---- log_softmax over pooled[2] + N*fcb ----
__global__ void logsm_k(const float* __restrict__ pooled,
                        const float* __restrict__ fcb,
                        float* __restrict__ out, float Nf) {
    if (threadIdx.x == 0 && blockIdx.x == 0) {
        float p0 = pooled[0] + Nf * fcb[0];
        float p1 = pooled[1] + Nf * fcb[1];
        float m = fmaxf(p0, p1);
        float lse = m + logf(expf(p0 - m) + expf(p1 - m));
        out[0] = p0 - lse;
        out[1] = p1 - lse;
    }
}

extern "C" void kernel_launch(void* const* d_in, const int* in_sizes, int n_in,
                              void* d_out, int out_size, void* d_ws, size_t ws_size,
                              hipStream_t stream) {
    const float* x   = (const float*)d_in[0];
    const int*   ei  = (const int*)d_in[1];
    const float* W1  = (const float*)d_in[2];
    const float* b1  = (const float*)d_in[3];
    const float* W2  = (const float*)d_in[4];
    const float* b2  = (const float*)d_in[5];
    const float* fcW = (const float*)d_in[6];
    const float* fcb = (const float*)d_in[7];
    float* out = (float*)d_out;

    int N = in_sizes[0] / NF_IN;
    int E = in_sizes[1] / 2;
    const int* row = ei;
    const int* col = ei + E;

    int nb   = (N + BPB - 1) / BPB;     // coarse buckets (391)
    int nblk = (E + EPB - 1) / EPB;     // partition blocks (391)

    // ws layout (4B units):
    // [starts N+1 | bstarts nb+1 | gbcnt nb | gcur nb | dinv N |
    //  h1p 16N (also v2) | z1p 16N | pooled 2 | sorted E | staging E]
    int*   ws_i    = (int*)d_ws;
    int*   starts  = ws_i;
    int*   bstarts = ws_i + (size_t)N + 1;
    int*   gbcnt   = bstarts + nb + 1;
    int*   gcur    = gbcnt + nb;
    float* dinv    = (float*)(gcur + nb);
    float* h1p     = dinv + N;
    float* z1p     = h1p + (size_t)16 * N;
    float* pooled  = z1p + (size_t)16 * N;
    int*   sorted  = (int*)(pooled + 2);
    int*   staging = sorted + (size_t)E;

    hipMemsetAsync(gbcnt, 0, (size_t)nb * sizeof(int), stream);
    hipMemsetAsync(pooled, 0, 2 * sizeof(float), stream);

    int b = 256;
    cnt1_k<<<nblk, 256, 0, stream>>>(col, gbcnt, E, N, nb);
    bscan_k<<<1, 512, 0, stream>>>(gbcnt, bstarts, gcur, nb);
    place_k<<<nblk, 256, 0, stream>>>(row, col, gcur, staging, E, N, nb);
    node_k<<<nb, 256, 0, stream>>>(staging, bstarts, starts, dinv, sorted, N, nb);
    xw1_k<<<(N + 15) / 16, b, 0, stream>>>(x, W1, dinv, h1p, N);
    long long t4 = (long long)N * 4;
    gather16<<<(int)((t4 + b - 1) / b), b, 0, stream>>>(
        sorted, starts, dinv, h1p, b1, z1p, N, 1);
    gather16<<<(int)((t4 + b - 1) / b), b, 0, stream>>>(
        sorted, starts, dinv, z1p, b1, h1p, N, 0);
    final_k<<<(N + b - 1) / b, b, 0, stream>>>(h1p, W2, b2, fcW, pooled, N);
    logsm_k<<<1, 64, 0, stream>>>(pooled, fcb, out, (float)N);
}